// Round 24
// baseline (97.255 us; speedup 1.0000x reference)
//
#include <hip/hip_runtime.h>
#include <hip/hip_fp16.h>
#include <math.h>

// Per-row int4 symmetric quantization — golden semantics PINNED BY PROBES
// (R17/R18/R19/R21/R22/R23):
//   s32 = RTP_f32(mm / 7)   i.e. CR result bumped +1 ulp32 when the exact
//                           residual e2 = mm - 7*s32 > 0 (inexact, rounded
//                           down). Round-toward-+inf semantics at f32.
//   s   = f16_RNE(s32), widened                  -> scales output
//   q   = clip( rintf( RN_f32(x / s) ), -8, 7 )  -> CR f32 quotient
//
// Probe evidence: flips only on rows with s32 rem in {0xFFE,0xFFF} AND
// e2 > 0 (R23 class A; B/C/D null) -> +1-ulp-iff-rounded-down, no down
// shifts (R17/R22-D), displacement one f16 ulp (R19), sparse rows (R18),
// quotient CR on scale-agreeing rows (R18 window null).
//
// Flag-proof: Markstein (C7 = RNE(1/7)) gives guaranteed RN_f32(mm/7);
// e2 via fmaf is the exact residual; bump is integer bit-inc; CR
// reciprocal via f64 Newton (innocuous double rounding, s is 11-bit);
// Markstein quotient with CR reciprocal == RN_f32(a/s); rintf = half-even.

#define COLS 4096

__global__ __launch_bounds__(256) void quant_rows_kernel(
    const float* __restrict__ x,
    float* __restrict__ q_out,      // [rows*4096] f32 (integer-valued)
    float* __restrict__ scale_out)  // [rows] f32 (f16-rounded values)
{
#pragma clang fp reassociate(off) contract(off)
    const int row = blockIdx.x;
    const int t   = threadIdx.x;

    const float4* __restrict__ xrow =
        reinterpret_cast<const float4*>(x + (size_t)row * COLS);

    // Load 16 floats/thread, coalesced: vec index k*256 + t
    float4 v[4];
    float m = 0.0f;
#pragma unroll
    for (int k = 0; k < 4; ++k) {
        v[k] = xrow[k * 256 + t];
        m = fmaxf(m, fmaxf(fmaxf(fabsf(v[k].x), fabsf(v[k].y)),
                           fmaxf(fabsf(v[k].z), fabsf(v[k].w))));
    }

    // Wave-64 butterfly max reduce
#pragma unroll
    for (int off = 1; off < 64; off <<= 1)
        m = fmaxf(m, __shfl_xor(m, off, 64));

    // Combine the 4 waves of the block
    __shared__ float smax[4];
    const int wid = t >> 6;
    if ((t & 63) == 0) smax[wid] = m;
    __syncthreads();
    const float mm = fmaxf(fmaxf(smax[0], smax[1]), fmaxf(smax[2], smax[3]));

    // ---- s32 = RN_f32(mm/7) via flag-proof Markstein ----
    const float C7  = 1.0f / 7.0f;          // constant-folded RNE(1/7)
    const float sq0 = mm * C7;
    const float se  = fmaf(-7.0f, sq0, mm); // exact residual of candidate
    float s32 = fmaf(se, C7, sq0);          // == RN_f32(mm/7), guaranteed

    // ---- RTP bump: +1 ulp32 iff exact residual > 0 (rounded down) ----
    const float e2 = fmaf(-7.0f, s32, mm);  // exact: mm - 7*s32
    if (e2 > 0.0f) {
        uint32_t u = __float_as_uint(s32);  // s32 > 0, normal
        s32 = __uint_as_float(u + 1u);      // next representable upward
    }

    // ---- s = f16_RNE(s32), widened ----
    const float s = __half2float(__float2half(s32));

    // ---- r = RN_f32(1/s): flag-proof f64 Newton, innocuous dbl-round ----
    const double sd = (double)s;
    double rd = (double)__builtin_amdgcn_rcpf(s);
    rd = fma(fma(-sd, rd, 1.0), rd, rd);
    rd = fma(fma(-sd, rd, 1.0), rd, rd);
    const float r = (float)rd;              // == RN_f32(1/s)

    // ---- quantize: q = clip(rintf(RN_f32(a/s)), -8, 7) ----
    float4* __restrict__ qrow =
        reinterpret_cast<float4*>(q_out + (size_t)row * COLS);
#pragma unroll
    for (int k = 0; k < 4; ++k) {
        float av[4] = { v[k].x, v[k].y, v[k].z, v[k].w };
        float ov[4];
#pragma unroll
        for (int j = 0; j < 4; ++j) {
            const float a  = av[j];
            const float q0 = a * r;
            const float y  = fmaf(fmaf(-s, q0, a), r, q0); // RN_f32(a/s)
            ov[j] = fminf(fmaxf(rintf(y), -8.0f), 7.0f);
        }
        float4 o; o.x = ov[0]; o.y = ov[1]; o.z = ov[2]; o.w = ov[3];
        qrow[k * 256 + t] = o;
    }

    if (t == 0) scale_out[row] = s;
}

extern "C" void kernel_launch(void* const* d_in, const int* in_sizes, int n_in,
                              void* d_out, int out_size, void* d_ws, size_t ws_size,
                              hipStream_t stream) {
    const float* x = (const float*)d_in[0];
    const int n    = in_sizes[0];          // rows * 4096
    const int rows = n / COLS;

    float* q_out     = (float*)d_out;      // first n elements: q as f32
    float* scale_out = (float*)d_out + n;  // next `rows` elements: scales as f32

    quant_rows_kernel<<<rows, 256, 0, stream>>>(x, q_out, scale_out);
}

// Round 26
// 88.488 us; speedup vs baseline: 1.0991x; 1.0991x over previous
//
#include <hip/hip_runtime.h>
#include <hip/hip_fp16.h>
#include <math.h>

// Per-row int4 symmetric quantization — golden semantics pinned by probes
// R17-R23 and VERIFIED PASSING (R24, absmax 0.0, 97.25 us):
//   s32 = RTP_f32(mm / 7)  (CR result +1 ulp32 iff exact residual > 0)
//   s   = f16_RNE(s32), widened                  -> scales output
//   q   = clip( rintf( RN_f32(x / s) ), -8, 7 )  -> CR f32 quotient
//
// R26: nontemporal loads/stores via native clang vector type (HIP float4
// is a struct the builtin rejects). Arithmetic bit-identical to R24.

#define COLS 4096

typedef float f32x4 __attribute__((ext_vector_type(4)));

__global__ __launch_bounds__(256) void quant_rows_kernel(
    const float* __restrict__ x,
    float* __restrict__ q_out,      // [rows*4096] f32 (integer-valued)
    float* __restrict__ scale_out)  // [rows] f32 (f16-rounded values)
{
#pragma clang fp reassociate(off) contract(off)
    const int row = blockIdx.x;
    const int t   = threadIdx.x;

    const f32x4* __restrict__ xrow =
        reinterpret_cast<const f32x4*>(x + (size_t)row * COLS);

    // Load 16 floats/thread, coalesced, nontemporal (read-once stream)
    f32x4 v[4];
    float m = 0.0f;
#pragma unroll
    for (int k = 0; k < 4; ++k) {
        v[k] = __builtin_nontemporal_load(&xrow[k * 256 + t]);
        m = fmaxf(m, fmaxf(fmaxf(fabsf(v[k].x), fabsf(v[k].y)),
                           fmaxf(fabsf(v[k].z), fabsf(v[k].w))));
    }

    // Wave-64 butterfly max reduce
#pragma unroll
    for (int off = 1; off < 64; off <<= 1)
        m = fmaxf(m, __shfl_xor(m, off, 64));

    // Combine the 4 waves of the block
    __shared__ float smax[4];
    const int wid = t >> 6;
    if ((t & 63) == 0) smax[wid] = m;
    __syncthreads();
    const float mm = fmaxf(fmaxf(smax[0], smax[1]), fmaxf(smax[2], smax[3]));

    // ---- s32 = RN_f32(mm/7) via flag-proof Markstein ----
    const float C7  = 1.0f / 7.0f;          // constant-folded RNE(1/7)
    const float sq0 = mm * C7;
    const float se  = fmaf(-7.0f, sq0, mm); // exact residual of candidate
    float s32 = fmaf(se, C7, sq0);          // == RN_f32(mm/7), guaranteed

    // ---- RTP bump: +1 ulp32 iff exact residual > 0 (rounded down) ----
    const float e2 = fmaf(-7.0f, s32, mm);  // exact: mm - 7*s32
    if (e2 > 0.0f) {
        uint32_t u = __float_as_uint(s32);  // s32 > 0, normal
        s32 = __uint_as_float(u + 1u);      // next representable upward
    }

    // ---- s = f16_RNE(s32), widened ----
    const float s = __half2float(__float2half(s32));

    // ---- r = RN_f32(1/s): flag-proof f64 Newton, innocuous dbl-round ----
    const double sd = (double)s;
    double rd = (double)__builtin_amdgcn_rcpf(s);
    rd = fma(fma(-sd, rd, 1.0), rd, rd);
    rd = fma(fma(-sd, rd, 1.0), rd, rd);
    const float r = (float)rd;              // == RN_f32(1/s)

    // ---- quantize: q = clip(rintf(RN_f32(a/s)), -8, 7), nt stores ----
    f32x4* __restrict__ qrow =
        reinterpret_cast<f32x4*>(q_out + (size_t)row * COLS);
#pragma unroll
    for (int k = 0; k < 4; ++k) {
        f32x4 o;
#pragma unroll
        for (int j = 0; j < 4; ++j) {
            const float a  = v[k][j];
            const float q0 = a * r;
            const float y  = fmaf(fmaf(-s, q0, a), r, q0); // RN_f32(a/s)
            o[j] = fminf(fmaxf(rintf(y), -8.0f), 7.0f);
        }
        __builtin_nontemporal_store(o, &qrow[k * 256 + t]);
    }

    if (t == 0) scale_out[row] = s;
}

extern "C" void kernel_launch(void* const* d_in, const int* in_sizes, int n_in,
                              void* d_out, int out_size, void* d_ws, size_t ws_size,
                              hipStream_t stream) {
    const float* x = (const float*)d_in[0];
    const int n    = in_sizes[0];          // rows * 4096
    const int rows = n / COLS;

    float* q_out     = (float*)d_out;      // first n elements: q as f32
    float* scale_out = (float*)d_out + n;  // next `rows` elements: scales as f32

    quant_rows_kernel<<<rows, 256, 0, stream>>>(x, q_out, scale_out);
}